// Round 5
// baseline (292.144 us; speedup 1.0000x reference)
//
#include <hip/hip_runtime.h>
#include <hip/hip_fp16.h>

// MIND-SSC loss, N=2, C=1, D=H=W=128, radius=1, dilation=2.
// Round 5: single heavy pass + streaming reduce.
//  - pass 1 computes ssd once (x-folded staging, round-4 structure), stores
//    mind=ssd-min as fp16 (SoA quad planes) + unclipped var fp32 into d_ws
//  - pass 2 streams 235 MB back: clip var with global mean m, exp, sq-diff
//  - fallback to the round-4 recompute kernels if ws_size is too small
//  - nested clamps preserved exactly; /27 dropped (exact: scale-invariant)

#define DIM 128
#define HW (128 * 128)
#define DHW (128 * 128 * 128)
#define NVOX (2 * DHW)                 // 4,194,304 voxels per image
#define LOSS_COUNT (2.0 * 12.0 * DHW)

#define TS   16                        // tile side (y and x)
#define SY   18                        // xsum rows incl. y halo
#define NSP  (SY * TS)                 // 288 xsum positions
#define CHZ  16                        // z-chunk per block

#define ACC_OFF   0                    // 3 doubles
#define MIND_OFF  256                  // 6 quad-planes of uint2: 6*NVOX*8 B
#define MIND_BYTES (6ULL * NVOX * 8ULL)            // 201,326,592
#define VAR_OFF   (256ULL + MIND_BYTES)
#define VAR_BYTES (2ULL * NVOX * 4ULL)             // 33,554,432
#define WS_NEED   (VAR_OFF + VAR_BYTES)            // 234,881,280

typedef float f4 __attribute__((ext_vector_type(4)));

__device__ __forceinline__ int clampi(int v) {
    v = v < 0 ? 0 : v;
    return v > 127 ? 127 : v;
}

__device__ __forceinline__ void block_reduce_atomic(float v, double* dst) {
#pragma unroll
    for (int off = 32; off > 0; off >>= 1)
        v += __shfl_down(v, off, 64);
    __shared__ float red[4];
    int lane = threadIdx.x & 63;
    int wid  = threadIdx.x >> 6;
    if (lane == 0) red[wid] = v;
    __syncthreads();
    if (threadIdx.x == 0) {
        double t = (double)red[0] + (double)red[1] + (double)red[2] + (double)red[3];
        atomicAdd(dst, t);
    }
    __syncthreads();
}

// Per-thread staging descriptor: one xsum position (px in [0,16), py in [0,18)).
struct SPos {
    int y0, ym, yp;          // row offsets * DIM: gy, clamp(gy-2), clamp(gy+2)
    int cx[3], cm[3], cp[3]; // per-wx tap columns: c, clamp(c-2), clamp(c+2)
    int woff3;               // f4 index of this position's quad triple
};

__device__ __forceinline__ SPos make_spos(int p, int y0t, int x0t) {
    SPos q;
    int py = p >> 4, px = p & 15;
    int gy = clampi(y0t - 1 + py);
    int gx = x0t + px;
    q.y0 = gy * DIM; q.ym = clampi(gy - 2) * DIM; q.yp = clampi(gy + 2) * DIM;
#pragma unroll
    for (int wx = 0; wx < 3; ++wx) {
        int c = clampi(gx + wx - 1);   // box tap clamp (outer pad)
        q.cx[wx] = c;
        q.cm[wx] = clampi(c - 2);      // dilation clamp (inner pad)
        q.cp[wx] = clampi(c + 2);
    }
    q.woff3 = p * 3;
    return q;
}

__device__ __forceinline__ void stage_xsum(const float* __restrict__ im,
                                           int zm, int zc, int zp,
                                           const SPos& q, f4* __restrict__ P) {
    f4 a = (f4)0.0f, b = (f4)0.0f, c = (f4)0.0f;
#pragma unroll
    for (int wx = 0; wx < 3; ++wx) {
        float s0 = im[zm + q.y0 + q.cx[wx]];   // z-2
        float s1 = im[zc + q.y0 + q.cm[wx]];   // x-2
        float s2 = im[zc + q.ym + q.cx[wx]];   // y-2
        float s3 = im[zc + q.y0 + q.cp[wx]];   // x+2
        float s4 = im[zp + q.y0 + q.cx[wx]];   // z+2
        float s5 = im[zc + q.yp + q.cx[wx]];   // y+2
        float d;
        d = s1 - s0; a.x += d * d;
        d = s2 - s0; a.y += d * d;
        d = s2 - s1; a.z += d * d;
        d = s3 - s0; a.w += d * d;
        d = s3 - s2; b.x += d * d;
        d = s4 - s1; b.y += d * d;
        d = s4 - s2; b.z += d * d;
        d = s4 - s3; b.w += d * d;
        d = s5 - s0; c.x += d * d;
        d = s5 - s1; c.y += d * d;
        d = s5 - s3; c.z += d * d;
        d = s5 - s4; c.w += d * d;
    }
    P[q.woff3 + 0] = a;
    P[q.woff3 + 1] = b;
    P[q.woff3 + 2] = c;
}

__device__ __forceinline__ void box3y(const f4* __restrict__ P,
                                      int ty, int tx, f4 q[3]) {
    int base = (ty * TS + tx) * 3;
#pragma unroll
    for (int k = 0; k < 3; ++k)
        q[k] = P[base + k] + P[base + TS * 3 + k] + P[base + 2 * TS * 3 + k];
}

__device__ __forceinline__ float min12(const f4 v[3]) {
    float mn = v[0][0];
#pragma unroll
    for (int i = 0; i < 4; ++i)
        mn = fminf(mn, fminf(v[0][i], fminf(v[1][i], v[2][i])));
    return mn;
}

__device__ __forceinline__ float sum12(const f4 v[3]) {
    float sm = 0.0f;
#pragma unroll
    for (int i = 0; i < 4; ++i)
        sm += v[0][i] + v[1][i] + v[2][i];
    return sm;
}

__device__ __forceinline__ uint2 pack4h(f4 v) {
    __half2 lo = __floats2half2_rn(v.x, v.y);
    __half2 hi = __floats2half2_rn(v.z, v.w);
    uint2 r;
    r.x = *(unsigned int*)&lo;
    r.y = *(unsigned int*)&hi;
    return r;
}

// ---------- fast path: pass 1 (compute + persist), pass 2 (stream reduce) ----

__global__ __launch_bounds__(256, 4) void compute_kernel(const float* __restrict__ pred,
                                                         const float* __restrict__ targ,
                                                         double* __restrict__ sums,
                                                         uint2* __restrict__ mindb,
                                                         float* __restrict__ varb) {
    __shared__ f4 Xp[NSP * 3];
    __shared__ f4 Xt[NSP * 3];
    const int t = threadIdx.x;
    const int tile = blockIdx.x & 63, n = blockIdx.x >> 6;
    const int x0t = (tile & 7) * TS, y0t = (tile >> 3) * TS;
    const int z0 = blockIdx.y * CHZ;
    const float* ip = pred + (size_t)n * DHW;
    const float* tp = targ + (size_t)n * DHW;

    SPos pa = make_spos(t, y0t, x0t);
    const bool hasB = (t + 256) < NSP;
    SPos pb = make_spos(hasB ? (t + 256) : 0, y0t, x0t);

    const int ty = t >> 4, tx = t & 15;
    const int gy = y0t + ty, gx = x0t + tx;

    f4 Ap[3], Bp[3], At[3], Bt[3];
#pragma unroll
    for (int q = 0; q < 3; ++q) {
        Ap[q] = (f4)0.0f; Bp[q] = (f4)0.0f;
        At[q] = (f4)0.0f; Bt[q] = (f4)0.0f;
    }
    float vsump = 0.0f, vsumt = 0.0f;

    for (int tz = z0 - 1; tz <= z0 + CHZ; ++tz) {
        int zq = clampi(tz);
        int zc = zq * HW, zm = clampi(zq - 2) * HW, zp = clampi(zq + 2) * HW;
        stage_xsum(ip, zm, zc, zp, pa, Xp);
        stage_xsum(tp, zm, zc, zp, pa, Xt);
        if (hasB) {
            stage_xsum(ip, zm, zc, zp, pb, Xp);
            stage_xsum(tp, zm, zc, zp, pb, Xt);
        }
        __syncthreads();

        f4 qp[3], qt[3];
        box3y(Xp, ty, tx, qp);
        box3y(Xt, ty, tx, qt);
        __syncthreads();

        int ze = tz - 1;
        if (ze >= z0) {
            f4 vp[3], vt[3];
#pragma unroll
            for (int q = 0; q < 3; ++q) {
                vp[q] = Ap[q] + qp[q];
                vt[q] = At[q] + qt[q];
            }
            int v = ((n * DIM + ze) * DIM + gy) * DIM + gx;

            float mnp = min12(vp);
            float varp = sum12(vp) * (1.0f / 12.0f) - mnp;
            vsump += varp;
            varb[v] = varp;
#pragma unroll
            for (int q = 0; q < 3; ++q)
                mindb[(size_t)(q * 2 + 0) * NVOX + v] = pack4h(vp[q] - mnp);

            float mnt = min12(vt);
            float vart = sum12(vt) * (1.0f / 12.0f) - mnt;
            vsumt += vart;
            varb[NVOX + v] = vart;
#pragma unroll
            for (int q = 0; q < 3; ++q)
                mindb[(size_t)(q * 2 + 1) * NVOX + v] = pack4h(vt[q] - mnt);
        }
#pragma unroll
        for (int q = 0; q < 3; ++q) {
            Ap[q] = Bp[q] + qp[q]; Bp[q] = qp[q];
            At[q] = Bt[q] + qt[q]; Bt[q] = qt[q];
        }
    }

    block_reduce_atomic(vsump, &sums[0]);
    block_reduce_atomic(vsumt, &sums[1]);
}

__global__ __launch_bounds__(256) void reduce_kernel(const uint2* __restrict__ mindb,
                                                     const float* __restrict__ varb,
                                                     const double* __restrict__ sums,
                                                     double* __restrict__ loss_sum) {
    const int gid = blockIdx.x * 256 + threadIdx.x;
    const int v0 = gid * 2;                       // two voxels per thread

    float vals[2][2][12];                         // [img][voxel][ch] = mind
    float inv[2][2];                              // [img][voxel] = -1/var_clipped

#pragma unroll
    for (int img = 0; img < 2; ++img) {
        float m = (float)(sums[img] * (1.0 / (double)NVOX));
        float lo = m * 0.001f, hi = m * 1000.0f;
        float2 v2 = *(const float2*)(varb + (size_t)img * NVOX + v0);
        inv[img][0] = -1.0f / fminf(fmaxf(v2.x, lo), hi);
        inv[img][1] = -1.0f / fminf(fmaxf(v2.y, lo), hi);
#pragma unroll
        for (int q = 0; q < 3; ++q) {
            uint4 d = *(const uint4*)(mindb + (size_t)(q * 2 + img) * NVOX + v0);
            __half2 h;
            float2 f;
            h = *(__half2*)&d.x; f = __half22float2(h);
            vals[img][0][q * 4 + 0] = f.x; vals[img][0][q * 4 + 1] = f.y;
            h = *(__half2*)&d.y; f = __half22float2(h);
            vals[img][0][q * 4 + 2] = f.x; vals[img][0][q * 4 + 3] = f.y;
            h = *(__half2*)&d.z; f = __half22float2(h);
            vals[img][1][q * 4 + 0] = f.x; vals[img][1][q * 4 + 1] = f.y;
            h = *(__half2*)&d.w; f = __half22float2(h);
            vals[img][1][q * 4 + 2] = f.x; vals[img][1][q * 4 + 3] = f.y;
        }
    }

    float acc = 0.0f;
#pragma unroll
    for (int k = 0; k < 2; ++k)
#pragma unroll
        for (int c = 0; c < 12; ++c) {
            float ep = __expf(vals[0][k][c] * inv[0][k]);
            float et = __expf(vals[1][k][c] * inv[1][k]);
            float dd = ep - et;
            acc += dd * dd;
        }

    block_reduce_atomic(acc, loss_sum);
}

// ---------- fallback path (round-4 kernels, used when ws is too small) ------

__device__ __forceinline__ float mind_var_of(const f4 v[3]) {
    return sum12(v) * (1.0f / 12.0f) - min12(v);
}

__global__ __launch_bounds__(256, 4) void var_kernel(const float* __restrict__ pred,
                                                     const float* __restrict__ targ,
                                                     double* __restrict__ sums) {
    __shared__ f4 Xp[NSP * 3];
    __shared__ f4 Xt[NSP * 3];
    const int t = threadIdx.x;
    const int tile = blockIdx.x & 63, n = blockIdx.x >> 6;
    const int x0t = (tile & 7) * TS, y0t = (tile >> 3) * TS;
    const int z0 = blockIdx.y * CHZ;
    const float* ip = pred + (size_t)n * DHW;
    const float* tp = targ + (size_t)n * DHW;

    SPos pa = make_spos(t, y0t, x0t);
    const bool hasB = (t + 256) < NSP;
    SPos pb = make_spos(hasB ? (t + 256) : 0, y0t, x0t);

    const int ty = t >> 4, tx = t & 15;

    f4 Ap[3], Bp[3], At[3], Bt[3];
#pragma unroll
    for (int q = 0; q < 3; ++q) {
        Ap[q] = (f4)0.0f; Bp[q] = (f4)0.0f;
        At[q] = (f4)0.0f; Bt[q] = (f4)0.0f;
    }
    float vsump = 0.0f, vsumt = 0.0f;

    for (int tz = z0 - 1; tz <= z0 + CHZ; ++tz) {
        int zq = clampi(tz);
        int zc = zq * HW, zm = clampi(zq - 2) * HW, zp = clampi(zq + 2) * HW;
        stage_xsum(ip, zm, zc, zp, pa, Xp);
        stage_xsum(tp, zm, zc, zp, pa, Xt);
        if (hasB) {
            stage_xsum(ip, zm, zc, zp, pb, Xp);
            stage_xsum(tp, zm, zc, zp, pb, Xt);
        }
        __syncthreads();

        f4 qp[3], qt[3];
        box3y(Xp, ty, tx, qp);
        box3y(Xt, ty, tx, qt);
        __syncthreads();

        int ze = tz - 1;
        if (ze >= z0) {
            f4 vp[3], vt[3];
#pragma unroll
            for (int q = 0; q < 3; ++q) {
                vp[q] = Ap[q] + qp[q];
                vt[q] = At[q] + qt[q];
            }
            vsump += mind_var_of(vp);
            vsumt += mind_var_of(vt);
        }
#pragma unroll
        for (int q = 0; q < 3; ++q) {
            Ap[q] = Bp[q] + qp[q]; Bp[q] = qp[q];
            At[q] = Bt[q] + qt[q]; Bt[q] = qt[q];
        }
    }

    block_reduce_atomic(vsump, &sums[0]);
    block_reduce_atomic(vsumt, &sums[1]);
}

__global__ __launch_bounds__(256, 4) void loss_kernel(const float* __restrict__ pred,
                                                      const float* __restrict__ targ,
                                                      const double* __restrict__ sums,
                                                      double* __restrict__ loss_sum) {
    __shared__ f4 Xp[NSP * 3];
    __shared__ f4 Xt[NSP * 3];
    const int t = threadIdx.x;
    const int tile = blockIdx.x & 63, n = blockIdx.x >> 6;
    const int x0t = (tile & 7) * TS, y0t = (tile >> 3) * TS;
    const int z0 = blockIdx.y * CHZ;
    const float* ip = pred + (size_t)n * DHW;
    const float* tp = targ + (size_t)n * DHW;

    const float m_p = (float)(sums[0] * (1.0 / (double)NVOX));
    const float m_t = (float)(sums[1] * (1.0 / (double)NVOX));

    SPos pa = make_spos(t, y0t, x0t);
    const bool hasB = (t + 256) < NSP;
    SPos pb = make_spos(hasB ? (t + 256) : 0, y0t, x0t);

    const int ty = t >> 4, tx = t & 15;

    f4 Ap[3], Bp[3], At[3], Bt[3];
#pragma unroll
    for (int q = 0; q < 3; ++q) {
        Ap[q] = (f4)0.0f; Bp[q] = (f4)0.0f;
        At[q] = (f4)0.0f; Bt[q] = (f4)0.0f;
    }
    float lsum = 0.0f;

    for (int tz = z0 - 1; tz <= z0 + CHZ; ++tz) {
        int zq = clampi(tz);
        int zc = zq * HW, zm = clampi(zq - 2) * HW, zp = clampi(zq + 2) * HW;
        stage_xsum(ip, zm, zc, zp, pa, Xp);
        stage_xsum(tp, zm, zc, zp, pa, Xt);
        if (hasB) {
            stage_xsum(ip, zm, zc, zp, pb, Xp);
            stage_xsum(tp, zm, zc, zp, pb, Xt);
        }
        __syncthreads();

        f4 qp[3], qt[3];
        box3y(Xp, ty, tx, qp);
        box3y(Xt, ty, tx, qt);
        __syncthreads();

        int ze = tz - 1;
        if (ze >= z0) {
            f4 vp[3], vt[3];
#pragma unroll
            for (int q = 0; q < 3; ++q) {
                vp[q] = Ap[q] + qp[q];
                vt[q] = At[q] + qt[q];
            }
            float mnp = min12(vp), smp = sum12(vp);
            float mnt = min12(vt), smt = sum12(vt);
            float varp = smp * (1.0f / 12.0f) - mnp;
            varp = fminf(fmaxf(varp, m_p * 0.001f), m_p * 1000.0f);
            float invp = -1.0f / varp;
            float vart = smt * (1.0f / 12.0f) - mnt;
            vart = fminf(fmaxf(vart, m_t * 0.001f), m_t * 1000.0f);
            float invt = -1.0f / vart;

            float acc = 0.0f;
#pragma unroll
            for (int q = 0; q < 3; ++q)
#pragma unroll
                for (int i = 0; i < 4; ++i) {
                    float ep = __expf((vp[q][i] - mnp) * invp);
                    float et = __expf((vt[q][i] - mnt) * invt);
                    float dd = ep - et;
                    acc += dd * dd;
                }
            lsum += acc;
        }
#pragma unroll
        for (int q = 0; q < 3; ++q) {
            Ap[q] = Bp[q] + qp[q]; Bp[q] = qp[q];
            At[q] = Bt[q] + qt[q]; Bt[q] = qt[q];
        }
    }

    block_reduce_atomic(lsum, loss_sum);
}

__global__ void finalize_kernel(const double* __restrict__ loss_sum,
                                float* __restrict__ out) {
    out[0] = (float)(loss_sum[0] * (1.0 / LOSS_COUNT));
}

extern "C" void kernel_launch(void* const* d_in, const int* in_sizes, int n_in,
                              void* d_out, int out_size, void* d_ws, size_t ws_size,
                              hipStream_t stream) {
    const float* pred = (const float*)d_in[0];
    const float* targ = (const float*)d_in[1];
    float* out = (float*)d_out;
    double* acc = (double*)d_ws;   // [0]=sum_var_pred, [1]=sum_var_targ, [2]=loss_sum

    hipMemsetAsync(d_ws, 0, 3 * sizeof(double), stream);

    dim3 block(256);
    dim3 grid(128, 8);
    if (ws_size >= WS_NEED) {
        uint2* mindb = (uint2*)((char*)d_ws + MIND_OFF);
        float* varb  = (float*)((char*)d_ws + VAR_OFF);
        compute_kernel<<<grid, block, 0, stream>>>(pred, targ, acc, mindb, varb);
        reduce_kernel<<<NVOX / 512, block, 0, stream>>>(mindb, varb, acc, acc + 2);
    } else {
        var_kernel<<<grid, block, 0, stream>>>(pred, targ, acc);
        loss_kernel<<<grid, block, 0, stream>>>(pred, targ, acc, acc + 2);
    }
    finalize_kernel<<<1, 1, 0, stream>>>(acc + 2, out);
}

// Round 6
// 166.990 us; speedup vs baseline: 1.7495x; 1.7495x over previous
//
#include <hip/hip_runtime.h>

// MIND-SSC loss, N=2, C=1, D=H=W=128, radius=1, dilation=2.
// Round 6: single fused heavy pass + clip-binding detection.
//  - fused pass: x-folded staging (round-4 structure), pred/targ packed as
//    float2 (packed VALU), computes var sums + UNCLIPPED loss + global
//    min/max of var (order-preserving uint key atomics)
//  - flag kernel: clip binds iff min<m*0.001f or max>m*1000f (exact test:
//    fminf(fmaxf(v,lo),hi)==v iff lo<=v<=hi); for these inputs it never does
//  - fallback clipped loss kernel launches always, early-exits when flag clean
//  - nested clamps preserved exactly; /27 dropped (exact: scale-invariant)

#define DIM 128
#define HW (128 * 128)
#define DHW (128 * 128 * 128)
#define NVOX (2 * DHW)
#define LOSS_COUNT (2.0 * 12.0 * DHW)

#define TS   16                   // tile side (y and x)
#define SY   18                   // xsum rows incl. y halo
#define NSP  (SY * TS)            // 288 xsum positions
#define CHZ  16                   // z-chunk per block
#define PSTR 7                    // f4 stride per position (6 used + 1 pad:
                                  // 28-word lane stride tiles 32 banks per 8 lanes)

typedef float f4 __attribute__((ext_vector_type(4)));
typedef float f2 __attribute__((ext_vector_type(2)));

__device__ __forceinline__ int clampi(int v) {
    v = v < 0 ? 0 : v;
    return v > 127 ? 127 : v;
}

__device__ __forceinline__ unsigned fkey(float f) {
    unsigned u = __float_as_uint(f);
    return (u & 0x80000000u) ? ~u : (u | 0x80000000u);
}
__device__ __forceinline__ float fdec(unsigned k) {
    unsigned u = (k & 0x80000000u) ? (k ^ 0x80000000u) : ~k;
    return __uint_as_float(u);
}

__device__ __forceinline__ void block_reduce_atomic(float v, double* dst) {
#pragma unroll
    for (int off = 32; off > 0; off >>= 1)
        v += __shfl_down(v, off, 64);
    __shared__ float red[4];
    int lane = threadIdx.x & 63;
    int wid  = threadIdx.x >> 6;
    if (lane == 0) red[wid] = v;
    __syncthreads();
    if (threadIdx.x == 0) {
        double t = (double)red[0] + (double)red[1] + (double)red[2] + (double)red[3];
        atomicAdd(dst, t);
    }
    __syncthreads();
}

__device__ __forceinline__ void block_minmax_atomic(float mnp, float mxp,
                                                    float mnt, float mxt,
                                                    unsigned* keys) {
#pragma unroll
    for (int off = 32; off > 0; off >>= 1) {
        mnp = fminf(mnp, __shfl_down(mnp, off, 64));
        mxp = fmaxf(mxp, __shfl_down(mxp, off, 64));
        mnt = fminf(mnt, __shfl_down(mnt, off, 64));
        mxt = fmaxf(mxt, __shfl_down(mxt, off, 64));
    }
    __shared__ float r[4][4];
    int lane = threadIdx.x & 63, wid = threadIdx.x >> 6;
    if (lane == 0) { r[wid][0] = mnp; r[wid][1] = mxp; r[wid][2] = mnt; r[wid][3] = mxt; }
    __syncthreads();
    if (threadIdx.x == 0) {
        float a = fminf(fminf(r[0][0], r[1][0]), fminf(r[2][0], r[3][0]));
        float b = fmaxf(fmaxf(r[0][1], r[1][1]), fmaxf(r[2][1], r[3][1]));
        float c = fminf(fminf(r[0][2], r[1][2]), fminf(r[2][2], r[3][2]));
        float d = fmaxf(fmaxf(r[0][3], r[1][3]), fmaxf(r[2][3], r[3][3]));
        atomicMin(&keys[0], fkey(a));
        atomicMax(&keys[1], fkey(b));
        atomicMin(&keys[2], fkey(c));
        atomicMax(&keys[3], fkey(d));
    }
    __syncthreads();
}

// Per-thread staging descriptor: one xsum position (px in [0,16), py in [0,18)).
struct SPos {
    int y0, ym, yp;          // row offsets * DIM: gy, clamp(gy-2), clamp(gy+2)
    int cx[3], cm[3], cp[3]; // per-wx tap columns: c, clamp(c-2), clamp(c+2)
    int woff;                // f4 index of this position's quads
};

__device__ __forceinline__ SPos make_spos(int p, int y0t, int x0t, int stride) {
    SPos q;
    int py = p >> 4, px = p & 15;
    int gy = clampi(y0t - 1 + py);
    int gx = x0t + px;
    q.y0 = gy * DIM; q.ym = clampi(gy - 2) * DIM; q.yp = clampi(gy + 2) * DIM;
#pragma unroll
    for (int wx = 0; wx < 3; ++wx) {
        int c = clampi(gx + wx - 1);   // box tap clamp (outer pad)
        q.cx[wx] = c;
        q.cm[wx] = clampi(c - 2);      // dilation clamp (inner pad)
        q.cp[wx] = clampi(c + 2);
    }
    q.woff = p * stride;
    return q;
}

// ---------------- fused pass (packed pred/targ) ----------------

// Compute xsum for BOTH images at this position; write 6 f4 (12 float2 ch).
__device__ __forceinline__ void stage_pair(const float* __restrict__ ip,
                                           const float* __restrict__ tp,
                                           int zm, int zc, int zp,
                                           const SPos& q, f4* __restrict__ X) {
    f2 acc[12];
#pragma unroll
    for (int c = 0; c < 12; ++c) acc[c] = (f2)0.0f;
#pragma unroll
    for (int wx = 0; wx < 3; ++wx) {
        int o0 = zm + q.y0 + q.cx[wx];
        int o1 = zc + q.y0 + q.cm[wx];
        int o2 = zc + q.ym + q.cx[wx];
        int o3 = zc + q.y0 + q.cp[wx];
        int o4 = zp + q.y0 + q.cx[wx];
        int o5 = zc + q.yp + q.cx[wx];
        f2 s0 = {ip[o0], tp[o0]};
        f2 s1 = {ip[o1], tp[o1]};
        f2 s2 = {ip[o2], tp[o2]};
        f2 s3 = {ip[o3], tp[o3]};
        f2 s4 = {ip[o4], tp[o4]};
        f2 s5 = {ip[o5], tp[o5]};
        f2 d;
        d = s1 - s0; acc[0]  += d * d;
        d = s2 - s0; acc[1]  += d * d;
        d = s2 - s1; acc[2]  += d * d;
        d = s3 - s0; acc[3]  += d * d;
        d = s3 - s2; acc[4]  += d * d;
        d = s4 - s1; acc[5]  += d * d;
        d = s4 - s2; acc[6]  += d * d;
        d = s4 - s3; acc[7]  += d * d;
        d = s5 - s0; acc[8]  += d * d;
        d = s5 - s1; acc[9]  += d * d;
        d = s5 - s3; acc[10] += d * d;
        d = s5 - s4; acc[11] += d * d;
    }
#pragma unroll
    for (int k = 0; k < 6; ++k) {
        f4 w;
        w.x = acc[2 * k].x;     w.y = acc[2 * k].y;
        w.z = acc[2 * k + 1].x; w.w = acc[2 * k + 1].y;
        X[q.woff + k] = w;
    }
}

__device__ __forceinline__ void box3y_pair(const f4* __restrict__ X,
                                           int ty, int tx, f4 q[6]) {
    int b0 = ((ty + 0) * TS + tx) * PSTR;
    int b1 = ((ty + 1) * TS + tx) * PSTR;
    int b2 = ((ty + 2) * TS + tx) * PSTR;
#pragma unroll
    for (int k = 0; k < 6; ++k)
        q[k] = X[b0 + k] + X[b1 + k] + X[b2 + k];
}

__global__ __launch_bounds__(256, 4) void fused_kernel(const float* __restrict__ pred,
                                                       const float* __restrict__ targ,
                                                       double* __restrict__ acc,
                                                       unsigned* __restrict__ keys) {
    __shared__ f4 X[NSP * PSTR];
    const int t = threadIdx.x;
    const int tile = blockIdx.x & 63, n = blockIdx.x >> 6;
    const int x0t = (tile & 7) * TS, y0t = (tile >> 3) * TS;
    const int z0 = blockIdx.y * CHZ;
    const float* ip = pred + (size_t)n * DHW;
    const float* tp = targ + (size_t)n * DHW;

    SPos pa = make_spos(t, y0t, x0t, PSTR);
    const bool hasB = (t + 256) < NSP;
    SPos pb = make_spos(hasB ? (t + 256) : 0, y0t, x0t, PSTR);

    const int ty = t >> 4, tx = t & 15;

    f4 A[6], B[6];
#pragma unroll
    for (int k = 0; k < 6; ++k) { A[k] = (f4)0.0f; B[k] = (f4)0.0f; }

    float vsump = 0.0f, vsumt = 0.0f, lsum = 0.0f;
    float locmnp = 1e30f, locmxp = -1e30f, locmnt = 1e30f, locmxt = -1e30f;

    for (int tz = z0 - 1; tz <= z0 + CHZ; ++tz) {
        int zq = clampi(tz);
        int zc = zq * HW, zm = clampi(zq - 2) * HW, zp = clampi(zq + 2) * HW;
        stage_pair(ip, tp, zm, zc, zp, pa, X);
        if (hasB) stage_pair(ip, tp, zm, zc, zp, pb, X);
        __syncthreads();

        f4 q[6];
        box3y_pair(X, ty, tx, q);
        __syncthreads();

        int ze = tz - 1;
        if (ze >= z0) {
            f4 v[6];
#pragma unroll
            for (int k = 0; k < 6; ++k) v[k] = A[k] + q[k];

            float mnp = v[0][0], mnt = v[0][1];
            float smp = 0.0f, smt = 0.0f;
#pragma unroll
            for (int c = 0; c < 12; ++c) {
                float pv = v[c >> 1][(c & 1) * 2];
                float tv = v[c >> 1][(c & 1) * 2 + 1];
                mnp = fminf(mnp, pv); smp += pv;
                mnt = fminf(mnt, tv); smt += tv;
            }
            float varp = smp * (1.0f / 12.0f) - mnp;
            float vart = smt * (1.0f / 12.0f) - mnt;
            vsump += varp; vsumt += vart;
            locmnp = fminf(locmnp, varp); locmxp = fmaxf(locmxp, varp);
            locmnt = fminf(locmnt, vart); locmxt = fmaxf(locmxt, vart);

            float invp = -1.0f / varp;   // UNCLIPPED (validated by flag kernel)
            float invt = -1.0f / vart;
            float la = 0.0f;
#pragma unroll
            for (int c = 0; c < 12; ++c) {
                float pv = v[c >> 1][(c & 1) * 2];
                float tv = v[c >> 1][(c & 1) * 2 + 1];
                float ep = __expf((pv - mnp) * invp);
                float et = __expf((tv - mnt) * invt);
                float dd = ep - et;
                la += dd * dd;
            }
            lsum += la;
        }
#pragma unroll
        for (int k = 0; k < 6; ++k) { A[k] = B[k] + q[k]; B[k] = q[k]; }
    }

    block_reduce_atomic(vsump, &acc[0]);
    block_reduce_atomic(vsumt, &acc[1]);
    block_reduce_atomic(lsum,  &acc[2]);
    block_minmax_atomic(locmnp, locmxp, locmnt, locmxt, keys);
}

// ---------------- clip detection + fallback ----------------

__global__ void init_kernel(double* __restrict__ acc, unsigned* __restrict__ keys) {
    acc[0] = 0.0; acc[1] = 0.0; acc[2] = 0.0; acc[3] = 0.0;
    keys[0] = 0xFFFFFFFFu; keys[1] = 0u;      // pred min/max keys
    keys[2] = 0xFFFFFFFFu; keys[3] = 0u;      // targ min/max keys
    keys[4] = 0u;                              // flag
}

__global__ void flag_kernel(const double* __restrict__ acc, unsigned* __restrict__ keys) {
    float m_p = (float)(acc[0] * (1.0 / (double)NVOX));
    float m_t = (float)(acc[1] * (1.0 / (double)NVOX));
    float mnp = fdec(keys[0]), mxp = fdec(keys[1]);
    float mnt = fdec(keys[2]), mxt = fdec(keys[3]);
    // clip leaves v unchanged iff lo <= v <= hi (same fp expressions as fallback)
    bool clean = (mnp >= m_p * 0.001f) && (mxp <= m_p * 1000.0f) &&
                 (mnt >= m_t * 0.001f) && (mxt <= m_t * 1000.0f);
    keys[4] = clean ? 0u : 1u;
}

__device__ __forceinline__ void stage_xsum(const float* __restrict__ im,
                                           int zm, int zc, int zp,
                                           const SPos& q, f4* __restrict__ P) {
    f4 a = (f4)0.0f, b = (f4)0.0f, c = (f4)0.0f;
#pragma unroll
    for (int wx = 0; wx < 3; ++wx) {
        float s0 = im[zm + q.y0 + q.cx[wx]];
        float s1 = im[zc + q.y0 + q.cm[wx]];
        float s2 = im[zc + q.ym + q.cx[wx]];
        float s3 = im[zc + q.y0 + q.cp[wx]];
        float s4 = im[zp + q.y0 + q.cx[wx]];
        float s5 = im[zc + q.yp + q.cx[wx]];
        float d;
        d = s1 - s0; a.x += d * d;
        d = s2 - s0; a.y += d * d;
        d = s2 - s1; a.z += d * d;
        d = s3 - s0; a.w += d * d;
        d = s3 - s2; b.x += d * d;
        d = s4 - s1; b.y += d * d;
        d = s4 - s2; b.z += d * d;
        d = s4 - s3; b.w += d * d;
        d = s5 - s0; c.x += d * d;
        d = s5 - s1; c.y += d * d;
        d = s5 - s3; c.z += d * d;
        d = s5 - s4; c.w += d * d;
    }
    P[q.woff + 0] = a;
    P[q.woff + 1] = b;
    P[q.woff + 2] = c;
}

__device__ __forceinline__ void box3y(const f4* __restrict__ P,
                                      int ty, int tx, f4 q[3]) {
    int base = (ty * TS + tx) * 3;
#pragma unroll
    for (int k = 0; k < 3; ++k)
        q[k] = P[base + k] + P[base + TS * 3 + k] + P[base + 2 * TS * 3 + k];
}

__device__ __forceinline__ float min12(const f4 v[3]) {
    float mn = v[0][0];
#pragma unroll
    for (int i = 0; i < 4; ++i)
        mn = fminf(mn, fminf(v[0][i], fminf(v[1][i], v[2][i])));
    return mn;
}
__device__ __forceinline__ float sum12(const f4 v[3]) {
    float sm = 0.0f;
#pragma unroll
    for (int i = 0; i < 4; ++i)
        sm += v[0][i] + v[1][i] + v[2][i];
    return sm;
}

// Fallback: full clipped recompute (round-4 loss kernel). Early-exits when
// the flag says no voxel clips (expected case for these inputs).
__global__ __launch_bounds__(256, 4) void loss_kernel(const float* __restrict__ pred,
                                                      const float* __restrict__ targ,
                                                      const double* __restrict__ acc,
                                                      const unsigned* __restrict__ keys,
                                                      double* __restrict__ loss_sum) {
    if (keys[4] == 0u) return;    // block-uniform

    __shared__ f4 Xp[NSP * 3];
    __shared__ f4 Xt[NSP * 3];
    const int t = threadIdx.x;
    const int tile = blockIdx.x & 63, n = blockIdx.x >> 6;
    const int x0t = (tile & 7) * TS, y0t = (tile >> 3) * TS;
    const int z0 = blockIdx.y * CHZ;
    const float* ip = pred + (size_t)n * DHW;
    const float* tp = targ + (size_t)n * DHW;

    const float m_p = (float)(acc[0] * (1.0 / (double)NVOX));
    const float m_t = (float)(acc[1] * (1.0 / (double)NVOX));

    SPos pa = make_spos(t, y0t, x0t, 3);
    const bool hasB = (t + 256) < NSP;
    SPos pb = make_spos(hasB ? (t + 256) : 0, y0t, x0t, 3);

    const int ty = t >> 4, tx = t & 15;

    f4 Ap[3], Bp[3], At[3], Bt[3];
#pragma unroll
    for (int q = 0; q < 3; ++q) {
        Ap[q] = (f4)0.0f; Bp[q] = (f4)0.0f;
        At[q] = (f4)0.0f; Bt[q] = (f4)0.0f;
    }
    float lsum = 0.0f;

    for (int tz = z0 - 1; tz <= z0 + CHZ; ++tz) {
        int zq = clampi(tz);
        int zc = zq * HW, zm = clampi(zq - 2) * HW, zp = clampi(zq + 2) * HW;
        stage_xsum(ip, zm, zc, zp, pa, Xp);
        stage_xsum(tp, zm, zc, zp, pa, Xt);
        if (hasB) {
            stage_xsum(ip, zm, zc, zp, pb, Xp);
            stage_xsum(tp, zm, zc, zp, pb, Xt);
        }
        __syncthreads();

        f4 qp[3], qt[3];
        box3y(Xp, ty, tx, qp);
        box3y(Xt, ty, tx, qt);
        __syncthreads();

        int ze = tz - 1;
        if (ze >= z0) {
            f4 vp[3], vt[3];
#pragma unroll
            for (int q = 0; q < 3; ++q) {
                vp[q] = Ap[q] + qp[q];
                vt[q] = At[q] + qt[q];
            }
            float mnp = min12(vp), smp = sum12(vp);
            float mnt = min12(vt), smt = sum12(vt);
            float varp = smp * (1.0f / 12.0f) - mnp;
            varp = fminf(fmaxf(varp, m_p * 0.001f), m_p * 1000.0f);
            float invp = -1.0f / varp;
            float vart = smt * (1.0f / 12.0f) - mnt;
            vart = fminf(fmaxf(vart, m_t * 0.001f), m_t * 1000.0f);
            float invt = -1.0f / vart;

            float a = 0.0f;
#pragma unroll
            for (int q = 0; q < 3; ++q)
#pragma unroll
                for (int i = 0; i < 4; ++i) {
                    float ep = __expf((vp[q][i] - mnp) * invp);
                    float et = __expf((vt[q][i] - mnt) * invt);
                    float dd = ep - et;
                    a += dd * dd;
                }
            lsum += a;
        }
#pragma unroll
        for (int q = 0; q < 3; ++q) {
            Ap[q] = Bp[q] + qp[q]; Bp[q] = qp[q];
            At[q] = Bt[q] + qt[q]; Bt[q] = qt[q];
        }
    }

    block_reduce_atomic(lsum, loss_sum);
}

__global__ void finalize_kernel(const double* __restrict__ acc,
                                const unsigned* __restrict__ keys,
                                float* __restrict__ out) {
    double l = (keys[4] == 0u) ? acc[2] : acc[3];
    out[0] = (float)(l * (1.0 / LOSS_COUNT));
}

extern "C" void kernel_launch(void* const* d_in, const int* in_sizes, int n_in,
                              void* d_out, int out_size, void* d_ws, size_t ws_size,
                              hipStream_t stream) {
    const float* pred = (const float*)d_in[0];
    const float* targ = (const float*)d_in[1];
    float* out = (float*)d_out;
    double* acc = (double*)d_ws;                    // [0]=vsum_p [1]=vsum_t [2]=loss_unclip [3]=loss_clip
    unsigned* keys = (unsigned*)((char*)d_ws + 64); // [0..3]=min/max keys, [4]=flag

    dim3 block(256);
    dim3 grid(128, 8);   // 64 tiles * 2 batch, 8 z-chunks of 16

    init_kernel<<<1, 1, 0, stream>>>(acc, keys);
    fused_kernel<<<grid, block, 0, stream>>>(pred, targ, acc, keys);
    flag_kernel<<<1, 1, 0, stream>>>(acc, keys);
    loss_kernel<<<grid, block, 0, stream>>>(pred, targ, acc, keys, &acc[3]);
    finalize_kernel<<<1, 1, 0, stream>>>(acc, keys, out);
}